// Round 6
// baseline (1535.543 us; speedup 1.0000x reference)
//
#include <hip/hip_runtime.h>
#include <hip/hip_bf16.h>

// ---------------------------------------------------------------------------
// PUSCH neural detector: 4 stacked ConvLSTM layers on [B=2,T=14,H=1536,W=1].
// 3x3 conv degenerates to width-3 conv along H (kw=1 slice). f32 throughout.
// Round 6: step kernel split over f (4x blocks, s-slowest grid order),
//          Ws bank-conflict swizzle in the GEMM.
// ---------------------------------------------------------------------------

#define BB   2
#define TT   14
#define LL   1536
#define CINR 297
#define CINP 304

// ---- workspace layout (units: f32 elements) -------------------------------
static constexpr size_t SZ_WXIN  = (size_t)3*CINP*256;
static constexpr size_t SZ_WH64  = (size_t)3*64*256;
static constexpr size_t SZ_WXOUT = (size_t)3*64*128;
static constexpr size_t SZ_WHOUT = (size_t)3*32*128;

static constexpr size_t OFF_WXIN  = 0;
static constexpr size_t OFF_WHIN  = OFF_WXIN  + SZ_WXIN;
static constexpr size_t OFF_WXR0  = OFF_WHIN  + SZ_WH64;
static constexpr size_t OFF_WHR0  = OFF_WXR0  + SZ_WH64;
static constexpr size_t OFF_WXR1  = OFF_WHR0  + SZ_WH64;
static constexpr size_t OFF_WHR1  = OFF_WXR1  + SZ_WH64;
static constexpr size_t OFF_WXOUT = OFF_WHR1  + SZ_WH64;
static constexpr size_t OFF_WHOUT = OFF_WXOUT + SZ_WXOUT;
static constexpr size_t OFF_BIN   = OFF_WHOUT + SZ_WHOUT;
static constexpr size_t OFF_BR0   = OFF_BIN + 256;
static constexpr size_t OFF_BR1   = OFF_BR0 + 256;
static constexpr size_t OFF_BOUT  = OFF_BR1 + 256;
static constexpr size_t PREP_TOTAL = OFF_BOUT + 128;

static constexpr size_t OFF_Z0  = 524288;                 // f32 [28][1536][304]
static constexpr size_t SZ_Z0   = (size_t)BB*TT*LL*CINP;
static constexpr size_t OFF_XZ  = OFF_Z0 + SZ_Z0;         // f32 [28][1536][256]
static constexpr size_t SZ_XZ   = (size_t)BB*TT*LL*256;
static constexpr size_t OFF_SEQ = OFF_XZ + SZ_XZ;         // f32 [28][1536][64]
static constexpr size_t SZ_SEQ  = (size_t)BB*TT*LL*64;
static constexpr size_t OFF_HA  = OFF_SEQ + SZ_SEQ;
static constexpr size_t SZ_HST  = (size_t)BB*LL*64;
static constexpr size_t OFF_HB  = OFF_HA + SZ_HST;
static constexpr size_t OFF_CS  = OFF_HB + SZ_HST;
// ~112 MB total

__device__ __forceinline__ float hsig(float x) {
    return fminf(fmaxf(0.2f * x + 0.5f, 0.0f), 1.0f);
}

// ---------------------------------------------------------------------------
// prep_weights. Wx stored [k][ci][co'] with co' = f*4+g (gate-interleaved).
// Wh stored transposed [k][ci][f][gate4]. Biases permuted to co'.
// ---------------------------------------------------------------------------
__device__ __forceinline__ float wx_midP(const float* src, int Cin, int N, int idx) {
    int k = idx / (Cin * N); int r = idx - k * (Cin * N);
    int ci = r / N; int cop = r - ci * N;
    int Fo = N >> 2;
    int f = cop >> 2, g = cop & 3;
    return src[((size_t)(k * 3 + 1) * Cin + ci) * N + g * Fo + f];
}
__device__ __forceinline__ float wh_midT(const float* src, int F_, int idx) {
    int N4 = 4 * F_;
    int k = idx / (F_ * N4); int r = idx - k * (F_ * N4);
    int ci = r / N4; int fg = r - ci * N4;
    int f = fg >> 2, g = fg & 3;
    return src[((size_t)(k * 3 + 1) * F_ + ci) * N4 + g * F_ + f];
}

__global__ __launch_bounds__(256)
void prep_weights_kernel(const float* wx_in, const float* wh_in, const float* b_in,
                         const float* wx_r0, const float* wh_r0, const float* b_r0,
                         const float* wx_r1, const float* wh_r1, const float* b_r1,
                         const float* wx_out, const float* wh_out, const float* b_out,
                         float* __restrict__ ws)
{
    int idx = blockIdx.x * 256 + threadIdx.x;
    if (idx < (int)SZ_WXIN) {
        int k = idx / (CINP * 256); int r = idx - k * (CINP * 256);
        int ci = r >> 8; int cop = r & 255;
        float v = 0.0f;
        if (ci < CINR) {
            int f = cop >> 2, g = cop & 3;
            v = wx_in[((size_t)(k * 3 + 1) * CINR + ci) * 256 + g * 64 + f];
        }
        ws[OFF_WXIN + idx] = v; return;
    }
    idx -= (int)SZ_WXIN;
    if (idx < (int)SZ_WH64) { ws[OFF_WHIN + idx] = wh_midT(wh_in, 64, idx); return; }
    idx -= (int)SZ_WH64;
    if (idx < (int)SZ_WH64) { ws[OFF_WXR0 + idx] = wx_midP(wx_r0, 64, 256, idx); return; }
    idx -= (int)SZ_WH64;
    if (idx < (int)SZ_WH64) { ws[OFF_WHR0 + idx] = wh_midT(wh_r0, 64, idx); return; }
    idx -= (int)SZ_WH64;
    if (idx < (int)SZ_WH64) { ws[OFF_WXR1 + idx] = wx_midP(wx_r1, 64, 256, idx); return; }
    idx -= (int)SZ_WH64;
    if (idx < (int)SZ_WH64) { ws[OFF_WHR1 + idx] = wh_midT(wh_r1, 64, idx); return; }
    idx -= (int)SZ_WH64;
    if (idx < (int)SZ_WXOUT) { ws[OFF_WXOUT + idx] = wx_midP(wx_out, 64, 128, idx); return; }
    idx -= (int)SZ_WXOUT;
    if (idx < (int)SZ_WHOUT) { ws[OFF_WHOUT + idx] = wh_midT(wh_out, 32, idx); return; }
    idx -= (int)SZ_WHOUT;
    if (idx < 256) { int f = idx >> 2, g = idx & 3; ws[OFF_BIN + idx] = b_in[g * 64 + f]; return; }
    idx -= 256;
    if (idx < 256) { int f = idx >> 2, g = idx & 3; ws[OFF_BR0 + idx] = b_r0[g * 64 + f]; return; }
    idx -= 256;
    if (idx < 256) { int f = idx >> 2, g = idx & 3; ws[OFF_BR1 + idx] = b_r1[g * 64 + f]; return; }
    idx -= 256;
    if (idx < 128) { int f = idx >> 2, g = idx & 3; ws[OFF_BOUT + idx] = b_out[g * 32 + f]; return; }
}

// ---------------------------------------------------------------------------
// build_features: gather [y | h | err | no] -> z0 f32 [28][1536][304]
// ---------------------------------------------------------------------------
__global__ __launch_bounds__(256)
void build_features_kernel(const float* __restrict__ y,
                           const float* __restrict__ h,
                           const float* __restrict__ ev,
                           const float* __restrict__ no,
                           float* __restrict__ z0)
{
    long long idx = (long long)blockIdx.x * 256 + threadIdx.x;
    const long long total = (long long)BB * TT * LL * CINP;
    if (idx >= total) return;
    int c = (int)(idx % CINP);
    long long rest = idx / CINP;
    int l = (int)(rest % LL); rest /= LL;
    int t = (int)(rest % TT);
    int b = (int)(rest / TT);
    float v = 0.0f;
    if (c < 32) {
        int na = c >> 1, ri = c & 1;
        v = y[((((long long)b * 16 + na) * TT + t) * LL + l) * 2 + ri];
    } else if (c < 288) {
        int q = c - 32;
        int ri = q & 1, nspu = (q >> 1) & 1, nue = (q >> 2) & 3, na = q >> 4;
        v = h[((((((long long)b * 16 + na) * 4 + nue) * 2 + nspu) * TT + t) * LL + l) * 2 + ri];
    } else if (c < 296) {
        int q = c - 288; int nspu = q & 1, nue = q >> 1;
        v = ev[(((long long)(nue * 2 + nspu) * TT + t) * LL) + l];
    } else if (c == 296) {
        v = no[0];
    }
    z0[idx] = v;
}

// ---------------------------------------------------------------------------
// xz_gemm v3: A-tile transposed As[c][row] (pitch 136, conflict-free across
// wave quarters). Ws stored with bank-swizzle n -> n + (n>>5)*4 (pitch 144)
// so the 16-lane b128 reads hit each bank-quad at most 2-way (free).
// ---------------------------------------------------------------------------
__device__ __forceinline__ int wsw(int n) { return n + ((n >> 5) << 2); }

__global__ __launch_bounds__(256)
void xz_gemm_kernel(const float* __restrict__ A, int CinPitch,
                    const float* __restrict__ Wg, const float* __restrict__ bias,
                    float* __restrict__ out, int Ncol)
{
    __shared__ float As[16 * 136];     // [c][row], rows 0..129 valid
    __shared__ float Ws[3 * 16 * 144]; // swizzled rows
    const int tid = threadIdx.x;
    const int bt = blockIdx.y;
    const int l0 = blockIdx.x * 128;
    const int n0 = blockIdx.z * 128;
    const int mbase = (tid >> 4) * 8;
    const int nbase = (tid & 15) * 8;
    const int nsw0 = wsw(nbase);
    const int nsw1 = wsw(nbase + 4);

    float acc[8][8];
#pragma unroll
    for (int i = 0; i < 8; i++)
#pragma unroll
        for (int j = 0; j < 8; j++) acc[i][j] = 0.0f;

    for (int cc0 = 0; cc0 < CinPitch; cc0 += 16) {
        __syncthreads();
        // stage A rows l0-1 .. l0+128 (zero outside), 16 channels, transposed
        for (int idx = tid; idx < 130 * 16; idx += 256) {
            int r = idx >> 4, c = idx & 15;
            int row = l0 + r - 1;
            float v = 0.0f;
            if (row >= 0 && row < LL)
                v = A[((size_t)bt * LL + row) * CinPitch + cc0 + c];
            As[c * 136 + r] = v;
        }
        // stage W [3][16][128] swizzled, float4 granularity
        for (int i4 = tid; i4 < 3 * 16 * 32; i4 += 256) {
            int kh = i4 >> 9;
            int r2 = i4 & 511;
            int kk = r2 >> 5, n4 = r2 & 31;
            float4 w = *reinterpret_cast<const float4*>(
                &Wg[((size_t)kh * CinPitch + cc0 + kk) * Ncol + n0 + n4 * 4]);
            *reinterpret_cast<float4*>(&Ws[(kh * 16 + kk) * 144 + wsw(n4 * 4)]) = w;
        }
        __syncthreads();
        for (int kk = 0; kk < 16; ++kk) {
            float a[10];
            *reinterpret_cast<float4*>(&a[0]) =
                *reinterpret_cast<const float4*>(&As[kk * 136 + mbase]);
            *reinterpret_cast<float4*>(&a[4]) =
                *reinterpret_cast<const float4*>(&As[kk * 136 + mbase + 4]);
            *reinterpret_cast<float2*>(&a[8]) =
                *reinterpret_cast<const float2*>(&As[kk * 136 + mbase + 8]);
#pragma unroll
            for (int kh = 0; kh < 3; ++kh) {
                const float* wrow = &Ws[(kh * 16 + kk) * 144];
                float w[8];
                *reinterpret_cast<float4*>(&w[0]) =
                    *reinterpret_cast<const float4*>(&wrow[nsw0]);
                *reinterpret_cast<float4*>(&w[4]) =
                    *reinterpret_cast<const float4*>(&wrow[nsw1]);
#pragma unroll
                for (int i = 0; i < 8; i++)
#pragma unroll
                    for (int j = 0; j < 8; j++)
                        acc[i][j] = fmaf(a[i + kh], w[j], acc[i][j]);
            }
        }
    }
#pragma unroll
    for (int i = 0; i < 8; i++) {
        int row = l0 + mbase + i;
        float* orow = out + ((size_t)bt * LL + row) * Ncol + n0 + nbase;
        float4 o0, o1;
        o0.x = acc[i][0] + bias[n0 + nbase + 0];
        o0.y = acc[i][1] + bias[n0 + nbase + 1];
        o0.z = acc[i][2] + bias[n0 + nbase + 2];
        o0.w = acc[i][3] + bias[n0 + nbase + 3];
        o1.x = acc[i][4] + bias[n0 + nbase + 4];
        o1.y = acc[i][5] + bias[n0 + nbase + 5];
        o1.z = acc[i][6] + bias[n0 + nbase + 6];
        o1.w = acc[i][7] + bias[n0 + nbase + 7];
        *reinterpret_cast<float4*>(orow) = o0;
        *reinterpret_cast<float4*>(orow + 4) = o1;
    }
}

// ---------------------------------------------------------------------------
// lstm_step v3: f-dimension split across SPLIT blocks; block = 16 rows x
// 16 f-quads, one (row, f-quad) per thread. Grid ordered s-slowest so
// co-resident blocks share the same weight slice (L1 reuse).
// h_prev staged in LDS (pitch F_+4: row-groups hit distinct bank-quads).
// Weights read directly from global as float4 (coalesced, L1/L2-resident).
// h double-buffered across launches (halo race).
// ---------------------------------------------------------------------------
template <int F_, int SPLIT, bool RESID, bool OUTW>
__global__ __launch_bounds__(256)
void lstm_step_kernel(const float* __restrict__ xz,      // [28][1536][F_*4] gate-interleaved
                      const float4* __restrict__ Wh4,    // [3][F_][F_] float4 (i,f,g,o)
                      const float* __restrict__ hprev,   // [B][1536][F_]
                      float* __restrict__ hnext,
                      float* __restrict__ cstate,
                      float* seq,                        // layer in/out seq (or null)
                      float* __restrict__ dout,          // final output f32 (or null)
                      int t)
{
    constexpr int ROWS = 16;
    constexpr int FQ = F_ / SPLIT;      // f-quads per block (16)
    constexpr int HP = F_ + 4;          // padded Hs pitch
    __shared__ float Hs[(ROWS + 2) * HP];

    const int tid = threadIdx.x;
    const int nLb = LL / ROWS;          // 96
    const int s   = blockIdx.x / (BB * nLb);
    const int r2  = blockIdx.x % (BB * nLb);
    const int b   = r2 / nLb;
    const int l0  = (r2 % nLb) * ROWS;

    const int fq  = s * FQ + (tid & (FQ - 1));  // this thread's f index
    const int row = tid / FQ;                   // 0..15

    // stage h_prev rows l0-1 .. l0+16 (zeros at t==0 / edges)
    for (int idx = tid; idx < (ROWS + 2) * F_; idx += 256) {
        int r = idx / F_, c = idx % F_;
        int grow = l0 + r - 1;
        float v = 0.0f;
        if (t > 0 && grow >= 0 && grow < LL) v = hprev[((size_t)b * LL + grow) * F_ + c];
        Hs[r * HP + c] = v;
    }
    __syncthreads();

    float4 zh = make_float4(0.f, 0.f, 0.f, 0.f);
    if (t > 0) {
#pragma unroll
        for (int k = 0; k < 3; k++) {
            const float4* __restrict__ wk = Wh4 + (size_t)k * F_ * F_ + fq;
            const float* __restrict__ hk = &Hs[(row + k) * HP];
#pragma unroll 4
            for (int c4 = 0; c4 < F_; c4 += 4) {
                const float4 h4 = *reinterpret_cast<const float4*>(&hk[c4]);
                const float4 w0 = wk[(size_t)(c4 + 0) * F_];
                const float4 w1 = wk[(size_t)(c4 + 1) * F_];
                const float4 w2 = wk[(size_t)(c4 + 2) * F_];
                const float4 w3 = wk[(size_t)(c4 + 3) * F_];
                zh.x = fmaf(h4.x, w0.x, zh.x);
                zh.y = fmaf(h4.x, w0.y, zh.y);
                zh.z = fmaf(h4.x, w0.z, zh.z);
                zh.w = fmaf(h4.x, w0.w, zh.w);
                zh.x = fmaf(h4.y, w1.x, zh.x);
                zh.y = fmaf(h4.y, w1.y, zh.y);
                zh.z = fmaf(h4.y, w1.z, zh.z);
                zh.w = fmaf(h4.y, w1.w, zh.w);
                zh.x = fmaf(h4.z, w2.x, zh.x);
                zh.y = fmaf(h4.z, w2.y, zh.y);
                zh.z = fmaf(h4.z, w2.z, zh.z);
                zh.w = fmaf(h4.z, w2.w, zh.w);
                zh.x = fmaf(h4.w, w3.x, zh.x);
                zh.y = fmaf(h4.w, w3.y, zh.y);
                zh.z = fmaf(h4.w, w3.z, zh.z);
                zh.w = fmaf(h4.w, w3.w, zh.w);
            }
        }
    }

    const size_t btL = ((size_t)b * TT + t) * LL;
    const int l = l0 + row;
    const float4 z4 = *reinterpret_cast<const float4*>(
        &xz[(btL + l) * (size_t)(4 * F_) + fq * 4]);
    float zi = z4.x + zh.x;
    float zf = z4.y + zh.y;
    float zg = z4.z + zh.z;
    float zo = z4.w + zh.w;
    float ig = hsig(zi), fg = hsig(zf);
    float gg = tanhf(zg), og = hsig(zo);
    size_t soff = ((size_t)b * LL + l) * F_ + fq;
    float cp = (t > 0) ? cstate[soff] : 0.0f;
    float cn = fg * cp + ig * gg;
    float hn = og * tanhf(cn);
    cstate[soff] = cn;
    hnext[soff] = hn;
    if (OUTW) {
        // out[b][ue][spu][n*4+bit]; f = ue*8 + spu*4 + bit; n = t*L + l
        int ue = fq >> 3, spu = (fq >> 2) & 1, bit = fq & 3;
        size_t n = (size_t)t * LL + l;
        dout[(((size_t)b * 4 + ue) * 2 + spu) * ((size_t)TT * LL * 4) + n * 4 + bit] = hn;
    } else {
        float v = hn;
        if (RESID) v += seq[(btL + l) * F_ + fq];   // same idx, same thread
        seq[(btL + l) * F_ + fq] = v;
    }
}

// ---------------------------------------------------------------------------
extern "C" void kernel_launch(void* const* d_in, const int* in_sizes, int n_in,
                              void* d_out, int out_size, void* d_ws, size_t ws_size,
                              hipStream_t stream)
{
    (void)in_sizes; (void)n_in; (void)out_size; (void)ws_size;
    const float* y_ri   = (const float*)d_in[0];
    const float* h_ri   = (const float*)d_in[1];
    const float* evar   = (const float*)d_in[2];
    const float* no     = (const float*)d_in[3];
    const float* wx_in  = (const float*)d_in[4];
    const float* wh_in  = (const float*)d_in[5];
    const float* b_in   = (const float*)d_in[6];
    const float* wx_r0  = (const float*)d_in[7];
    const float* wh_r0  = (const float*)d_in[8];
    const float* b_r0   = (const float*)d_in[9];
    const float* wx_r1  = (const float*)d_in[10];
    const float* wh_r1  = (const float*)d_in[11];
    const float* b_r1   = (const float*)d_in[12];
    const float* wx_out = (const float*)d_in[13];
    const float* wh_out = (const float*)d_in[14];
    const float* b_out  = (const float*)d_in[15];

    float* ws = (float*)d_ws;
    float* dout = (float*)d_out;

    {
        int blocks = (int)((PREP_TOTAL + 255) / 256);
        prep_weights_kernel<<<blocks, 256, 0, stream>>>(
            wx_in, wh_in, b_in, wx_r0, wh_r0, b_r0,
            wx_r1, wh_r1, b_r1, wx_out, wh_out, b_out, ws);
    }
    {
        long long total = (long long)BB * TT * LL * CINP;
        int blocks = (int)((total + 255) / 256);
        build_features_kernel<<<blocks, 256, 0, stream>>>(
            y_ri, h_ri, evar, no, ws + OFF_Z0);
    }

    float* hA = ws + OFF_HA;
    float* hB = ws + OFF_HB;
    float* cs = ws + OFF_CS;
    float* seq = ws + OFF_SEQ;
    const dim3 g256(12, BB * TT, 2);
    const dim3 g128(12, BB * TT, 1);
    const int stepGrid64 = 4 * BB * (LL / 16);   // SPLIT=4 -> 768
    const int stepGrid32 = 2 * BB * (LL / 16);   // SPLIT=2 -> 384

    // ---- layer in: Cin=297(p304) -> F=64
    xz_gemm_kernel<<<g256, 256, 0, stream>>>(
        ws + OFF_Z0, CINP, ws + OFF_WXIN, ws + OFF_BIN, ws + OFF_XZ, 256);
    for (int t = 0; t < TT; t++)
        lstm_step_kernel<64, 4, false, false><<<stepGrid64, 256, 0, stream>>>(
            ws + OFF_XZ, (const float4*)(ws + OFF_WHIN),
            (t & 1) ? hB : hA, (t & 1) ? hA : hB, cs, seq, nullptr, t);

    // ---- layer r0 (+residual, in-place on seq)
    xz_gemm_kernel<<<g256, 256, 0, stream>>>(
        seq, 64, ws + OFF_WXR0, ws + OFF_BR0, ws + OFF_XZ, 256);
    for (int t = 0; t < TT; t++)
        lstm_step_kernel<64, 4, true, false><<<stepGrid64, 256, 0, stream>>>(
            ws + OFF_XZ, (const float4*)(ws + OFF_WHR0),
            (t & 1) ? hB : hA, (t & 1) ? hA : hB, cs, seq, nullptr, t);

    // ---- layer r1 (+residual, in-place on seq)
    xz_gemm_kernel<<<g256, 256, 0, stream>>>(
        seq, 64, ws + OFF_WXR1, ws + OFF_BR1, ws + OFF_XZ, 256);
    for (int t = 0; t < TT; t++)
        lstm_step_kernel<64, 4, true, false><<<stepGrid64, 256, 0, stream>>>(
            ws + OFF_XZ, (const float4*)(ws + OFF_WHR1),
            (t & 1) ? hB : hA, (t & 1) ? hA : hB, cs, seq, nullptr, t);

    // ---- layer out: F=32, writes d_out (f32, transposed layout)
    xz_gemm_kernel<<<g128, 256, 0, stream>>>(
        seq, 64, ws + OFF_WXOUT, ws + OFF_BOUT, ws + OFF_XZ, 128);
    for (int t = 0; t < TT; t++)
        lstm_step_kernel<32, 2, false, true><<<stepGrid32, 256, 0, stream>>>(
            ws + OFF_XZ, (const float4*)(ws + OFF_WHOUT),
            (t & 1) ? hB : hA, (t & 1) ? hA : hB, cs, nullptr, dout, t);
}

// Round 7
// 1361.435 us; speedup vs baseline: 1.1279x; 1.1279x over previous
//
#include <hip/hip_runtime.h>
#include <hip/hip_bf16.h>

// ---------------------------------------------------------------------------
// PUSCH neural detector: 4 stacked ConvLSTM layers on [B=2,T=14,H=1536,W=1].
// 3x3 conv degenerates to width-3 conv along H (kw=1 slice). f32 throughout.
// Round 7: ci-split step kernel (lane=f coalesced weights, 3 waves/SIMD,
//          LDS partial-sum exchange). GEMM unchanged from R6.
// ---------------------------------------------------------------------------

#define BB   2
#define TT   14
#define LL   1536
#define CINR 297
#define CINP 304

// ---- workspace layout (units: f32 elements) -------------------------------
static constexpr size_t SZ_WXIN  = (size_t)3*CINP*256;
static constexpr size_t SZ_WH64  = (size_t)3*64*256;
static constexpr size_t SZ_WXOUT = (size_t)3*64*128;
static constexpr size_t SZ_WHOUT = (size_t)3*32*128;

static constexpr size_t OFF_WXIN  = 0;
static constexpr size_t OFF_WHIN  = OFF_WXIN  + SZ_WXIN;
static constexpr size_t OFF_WXR0  = OFF_WHIN  + SZ_WH64;
static constexpr size_t OFF_WHR0  = OFF_WXR0  + SZ_WH64;
static constexpr size_t OFF_WXR1  = OFF_WHR0  + SZ_WH64;
static constexpr size_t OFF_WHR1  = OFF_WXR1  + SZ_WH64;
static constexpr size_t OFF_WXOUT = OFF_WHR1  + SZ_WH64;
static constexpr size_t OFF_WHOUT = OFF_WXOUT + SZ_WXOUT;
static constexpr size_t OFF_BIN   = OFF_WHOUT + SZ_WHOUT;
static constexpr size_t OFF_BR0   = OFF_BIN + 256;
static constexpr size_t OFF_BR1   = OFF_BR0 + 256;
static constexpr size_t OFF_BOUT  = OFF_BR1 + 256;
static constexpr size_t PREP_TOTAL = OFF_BOUT + 128;

static constexpr size_t OFF_Z0  = 524288;                 // f32 [28][1536][304]
static constexpr size_t SZ_Z0   = (size_t)BB*TT*LL*CINP;
static constexpr size_t OFF_XZ  = OFF_Z0 + SZ_Z0;         // f32 [28][1536][256]
static constexpr size_t SZ_XZ   = (size_t)BB*TT*LL*256;
static constexpr size_t OFF_SEQ = OFF_XZ + SZ_XZ;         // f32 [28][1536][64]
static constexpr size_t SZ_SEQ  = (size_t)BB*TT*LL*64;
static constexpr size_t OFF_HA  = OFF_SEQ + SZ_SEQ;
static constexpr size_t SZ_HST  = (size_t)BB*LL*64;
static constexpr size_t OFF_HB  = OFF_HA + SZ_HST;
static constexpr size_t OFF_CS  = OFF_HB + SZ_HST;
// ~112 MB total

__device__ __forceinline__ float hsig(float x) {
    return fminf(fmaxf(0.2f * x + 0.5f, 0.0f), 1.0f);
}

// ---------------------------------------------------------------------------
// prep_weights. Wx stored [k][ci][co'] with co' = f*4+g (gate-interleaved).
// Wh stored transposed [k][ci][f][gate4]. Biases permuted to co'.
// ---------------------------------------------------------------------------
__device__ __forceinline__ float wx_midP(const float* src, int Cin, int N, int idx) {
    int k = idx / (Cin * N); int r = idx - k * (Cin * N);
    int ci = r / N; int cop = r - ci * N;
    int Fo = N >> 2;
    int f = cop >> 2, g = cop & 3;
    return src[((size_t)(k * 3 + 1) * Cin + ci) * N + g * Fo + f];
}
__device__ __forceinline__ float wh_midT(const float* src, int F_, int idx) {
    int N4 = 4 * F_;
    int k = idx / (F_ * N4); int r = idx - k * (F_ * N4);
    int ci = r / N4; int fg = r - ci * N4;
    int f = fg >> 2, g = fg & 3;
    return src[((size_t)(k * 3 + 1) * F_ + ci) * N4 + g * F_ + f];
}

__global__ __launch_bounds__(256)
void prep_weights_kernel(const float* wx_in, const float* wh_in, const float* b_in,
                         const float* wx_r0, const float* wh_r0, const float* b_r0,
                         const float* wx_r1, const float* wh_r1, const float* b_r1,
                         const float* wx_out, const float* wh_out, const float* b_out,
                         float* __restrict__ ws)
{
    int idx = blockIdx.x * 256 + threadIdx.x;
    if (idx < (int)SZ_WXIN) {
        int k = idx / (CINP * 256); int r = idx - k * (CINP * 256);
        int ci = r >> 8; int cop = r & 255;
        float v = 0.0f;
        if (ci < CINR) {
            int f = cop >> 2, g = cop & 3;
            v = wx_in[((size_t)(k * 3 + 1) * CINR + ci) * 256 + g * 64 + f];
        }
        ws[OFF_WXIN + idx] = v; return;
    }
    idx -= (int)SZ_WXIN;
    if (idx < (int)SZ_WH64) { ws[OFF_WHIN + idx] = wh_midT(wh_in, 64, idx); return; }
    idx -= (int)SZ_WH64;
    if (idx < (int)SZ_WH64) { ws[OFF_WXR0 + idx] = wx_midP(wx_r0, 64, 256, idx); return; }
    idx -= (int)SZ_WH64;
    if (idx < (int)SZ_WH64) { ws[OFF_WHR0 + idx] = wh_midT(wh_r0, 64, idx); return; }
    idx -= (int)SZ_WH64;
    if (idx < (int)SZ_WH64) { ws[OFF_WXR1 + idx] = wx_midP(wx_r1, 64, 256, idx); return; }
    idx -= (int)SZ_WH64;
    if (idx < (int)SZ_WH64) { ws[OFF_WHR1 + idx] = wh_midT(wh_r1, 64, idx); return; }
    idx -= (int)SZ_WH64;
    if (idx < (int)SZ_WXOUT) { ws[OFF_WXOUT + idx] = wx_midP(wx_out, 64, 128, idx); return; }
    idx -= (int)SZ_WXOUT;
    if (idx < (int)SZ_WHOUT) { ws[OFF_WHOUT + idx] = wh_midT(wh_out, 32, idx); return; }
    idx -= (int)SZ_WHOUT;
    if (idx < 256) { int f = idx >> 2, g = idx & 3; ws[OFF_BIN + idx] = b_in[g * 64 + f]; return; }
    idx -= 256;
    if (idx < 256) { int f = idx >> 2, g = idx & 3; ws[OFF_BR0 + idx] = b_r0[g * 64 + f]; return; }
    idx -= 256;
    if (idx < 256) { int f = idx >> 2, g = idx & 3; ws[OFF_BR1 + idx] = b_r1[g * 64 + f]; return; }
    idx -= 256;
    if (idx < 128) { int f = idx >> 2, g = idx & 3; ws[OFF_BOUT + idx] = b_out[g * 32 + f]; return; }
}

// ---------------------------------------------------------------------------
// build_features: gather [y | h | err | no] -> z0 f32 [28][1536][304]
// ---------------------------------------------------------------------------
__global__ __launch_bounds__(256)
void build_features_kernel(const float* __restrict__ y,
                           const float* __restrict__ h,
                           const float* __restrict__ ev,
                           const float* __restrict__ no,
                           float* __restrict__ z0)
{
    long long idx = (long long)blockIdx.x * 256 + threadIdx.x;
    const long long total = (long long)BB * TT * LL * CINP;
    if (idx >= total) return;
    int c = (int)(idx % CINP);
    long long rest = idx / CINP;
    int l = (int)(rest % LL); rest /= LL;
    int t = (int)(rest % TT);
    int b = (int)(rest / TT);
    float v = 0.0f;
    if (c < 32) {
        int na = c >> 1, ri = c & 1;
        v = y[((((long long)b * 16 + na) * TT + t) * LL + l) * 2 + ri];
    } else if (c < 288) {
        int q = c - 32;
        int ri = q & 1, nspu = (q >> 1) & 1, nue = (q >> 2) & 3, na = q >> 4;
        v = h[((((((long long)b * 16 + na) * 4 + nue) * 2 + nspu) * TT + t) * LL + l) * 2 + ri];
    } else if (c < 296) {
        int q = c - 288; int nspu = q & 1, nue = q >> 1;
        v = ev[(((long long)(nue * 2 + nspu) * TT + t) * LL) + l];
    } else if (c == 296) {
        v = no[0];
    }
    z0[idx] = v;
}

// ---------------------------------------------------------------------------
// xz_gemm v3 (unchanged from R6): A-tile transposed As[c][row] (pitch 136),
// Ws swizzled pitch 144.
// ---------------------------------------------------------------------------
__device__ __forceinline__ int wsw(int n) { return n + ((n >> 5) << 2); }

__global__ __launch_bounds__(256)
void xz_gemm_kernel(const float* __restrict__ A, int CinPitch,
                    const float* __restrict__ Wg, const float* __restrict__ bias,
                    float* __restrict__ out, int Ncol)
{
    __shared__ float As[16 * 136];
    __shared__ float Ws[3 * 16 * 144];
    const int tid = threadIdx.x;
    const int bt = blockIdx.y;
    const int l0 = blockIdx.x * 128;
    const int n0 = blockIdx.z * 128;
    const int mbase = (tid >> 4) * 8;
    const int nbase = (tid & 15) * 8;
    const int nsw0 = wsw(nbase);
    const int nsw1 = wsw(nbase + 4);

    float acc[8][8];
#pragma unroll
    for (int i = 0; i < 8; i++)
#pragma unroll
        for (int j = 0; j < 8; j++) acc[i][j] = 0.0f;

    for (int cc0 = 0; cc0 < CinPitch; cc0 += 16) {
        __syncthreads();
        for (int idx = tid; idx < 130 * 16; idx += 256) {
            int r = idx >> 4, c = idx & 15;
            int row = l0 + r - 1;
            float v = 0.0f;
            if (row >= 0 && row < LL)
                v = A[((size_t)bt * LL + row) * CinPitch + cc0 + c];
            As[c * 136 + r] = v;
        }
        for (int i4 = tid; i4 < 3 * 16 * 32; i4 += 256) {
            int kh = i4 >> 9;
            int r2 = i4 & 511;
            int kk = r2 >> 5, n4 = r2 & 31;
            float4 w = *reinterpret_cast<const float4*>(
                &Wg[((size_t)kh * CinPitch + cc0 + kk) * Ncol + n0 + n4 * 4]);
            *reinterpret_cast<float4*>(&Ws[(kh * 16 + kk) * 144 + wsw(n4 * 4)]) = w;
        }
        __syncthreads();
        for (int kk = 0; kk < 16; ++kk) {
            float a[10];
            *reinterpret_cast<float4*>(&a[0]) =
                *reinterpret_cast<const float4*>(&As[kk * 136 + mbase]);
            *reinterpret_cast<float4*>(&a[4]) =
                *reinterpret_cast<const float4*>(&As[kk * 136 + mbase + 4]);
            *reinterpret_cast<float2*>(&a[8]) =
                *reinterpret_cast<const float2*>(&As[kk * 136 + mbase + 8]);
#pragma unroll
            for (int kh = 0; kh < 3; ++kh) {
                const float* wrow = &Ws[(kh * 16 + kk) * 144];
                float w[8];
                *reinterpret_cast<float4*>(&w[0]) =
                    *reinterpret_cast<const float4*>(&wrow[nsw0]);
                *reinterpret_cast<float4*>(&w[4]) =
                    *reinterpret_cast<const float4*>(&wrow[nsw1]);
#pragma unroll
                for (int i = 0; i < 8; i++)
#pragma unroll
                    for (int j = 0; j < 8; j++)
                        acc[i][j] = fmaf(a[i + kh], w[j], acc[i][j]);
            }
        }
    }
#pragma unroll
    for (int i = 0; i < 8; i++) {
        int row = l0 + mbase + i;
        float* orow = out + ((size_t)bt * LL + row) * Ncol + n0 + nbase;
        float4 o0, o1;
        o0.x = acc[i][0] + bias[n0 + nbase + 0];
        o0.y = acc[i][1] + bias[n0 + nbase + 1];
        o0.z = acc[i][2] + bias[n0 + nbase + 2];
        o0.w = acc[i][3] + bias[n0 + nbase + 3];
        o1.x = acc[i][4] + bias[n0 + nbase + 4];
        o1.y = acc[i][5] + bias[n0 + nbase + 5];
        o1.z = acc[i][6] + bias[n0 + nbase + 6];
        o1.w = acc[i][7] + bias[n0 + nbase + 7];
        *reinterpret_cast<float4*>(orow) = o0;
        *reinterpret_cast<float4*>(orow + 4) = o1;
    }
}

// ---------------------------------------------------------------------------
// lstm_step v4: ci-split. Block = 8 rows, 8*F_ threads:
//   f = tid % F_ (lane index -> coalesced weight float4 loads, 1KB/wave),
//   rg = row group (4 groups x R=2 rows), cis = K-half (0/1).
// Each thread accumulates its K/2 slice for 2 rows; cis=1 dumps partials to
// LDS; cis=0 adds them and runs the gate epilogue. 384 blocks -> 3 waves/SIMD
// (F=64). Wh flattened [3*F_][F_] float4; h staged in LDS with halo.
// h double-buffered across launches (halo race).
// ---------------------------------------------------------------------------
template <int F_, bool RESID, bool OUTW>
__global__ __launch_bounds__(8 * F_)
void lstm_step_kernel(const float* __restrict__ xz,      // [28][1536][F_*4] gate-interleaved
                      const float4* __restrict__ Wh4,    // [3*F_][F_] float4 (i,f,g,o)
                      const float* __restrict__ hprev,   // [B][1536][F_]
                      float* __restrict__ hnext,
                      float* __restrict__ cstate,
                      float* seq,                        // layer in/out seq (or null)
                      float* __restrict__ dout,          // final output f32 (or null)
                      int t)
{
    constexpr int ROWS = 8;
    constexpr int R    = 2;
    constexpr int RG   = ROWS / R;      // 4
    constexpr int K    = 3 * F_;
    constexpr int KH   = K / 2;
    constexpr int HP   = F_ + 4;
    constexpr int NT   = 8 * F_;
    __shared__ float Hs[(ROWS + 2) * HP];
    __shared__ float Ps[ROWS * F_ * 4];

    const int tid = threadIdx.x;
    const int f   = tid % F_;
    const int rg  = (tid / F_) % RG;
    const int cis = tid / (F_ * RG);    // 0 or 1
    const int nLb = LL / ROWS;          // 192
    const int b   = blockIdx.x / nLb;
    const int l0  = (blockIdx.x % nLb) * ROWS;
    const int rgR = rg * R;

    float4 zh[R];
#pragma unroll
    for (int i = 0; i < R; i++) zh[i] = make_float4(0.f, 0.f, 0.f, 0.f);

    if (t > 0) {
        // stage h_prev rows l0-1 .. l0+8 (zeros at edges)
        for (int idx = tid; idx < (ROWS + 2) * F_; idx += NT) {
            int r = idx / F_, c = idx % F_;
            int grow = l0 + r - 1;
            float v = 0.0f;
            if (grow >= 0 && grow < LL) v = hprev[((size_t)b * LL + grow) * F_ + c];
            Hs[r * HP + c] = v;
        }
        __syncthreads();

        const int c0 = cis * KH;
#pragma unroll 4
        for (int c4 = c0; c4 < c0 + KH; c4 += 4) {
            const int k  = c4 / F_;             // conv tap (F_ | boundaries)
            const int ci = c4 % F_;
            const float4 w0 = Wh4[(size_t)(c4 + 0) * F_ + f];
            const float4 w1 = Wh4[(size_t)(c4 + 1) * F_ + f];
            const float4 w2 = Wh4[(size_t)(c4 + 2) * F_ + f];
            const float4 w3 = Wh4[(size_t)(c4 + 3) * F_ + f];
#pragma unroll
            for (int i = 0; i < R; i++) {
                const float4 h4 = *reinterpret_cast<const float4*>(
                    &Hs[(rgR + i + k) * HP + ci]);
                zh[i].x = fmaf(h4.x, w0.x, zh[i].x);
                zh[i].y = fmaf(h4.x, w0.y, zh[i].y);
                zh[i].z = fmaf(h4.x, w0.z, zh[i].z);
                zh[i].w = fmaf(h4.x, w0.w, zh[i].w);
                zh[i].x = fmaf(h4.y, w1.x, zh[i].x);
                zh[i].y = fmaf(h4.y, w1.y, zh[i].y);
                zh[i].z = fmaf(h4.y, w1.z, zh[i].z);
                zh[i].w = fmaf(h4.y, w1.w, zh[i].w);
                zh[i].x = fmaf(h4.z, w2.x, zh[i].x);
                zh[i].y = fmaf(h4.z, w2.y, zh[i].y);
                zh[i].z = fmaf(h4.z, w2.z, zh[i].z);
                zh[i].w = fmaf(h4.z, w2.w, zh[i].w);
                zh[i].x = fmaf(h4.w, w3.x, zh[i].x);
                zh[i].y = fmaf(h4.w, w3.y, zh[i].y);
                zh[i].z = fmaf(h4.w, w3.z, zh[i].z);
                zh[i].w = fmaf(h4.w, w3.w, zh[i].w);
            }
        }

        // cis=1 -> partials to LDS; cis=0 -> add
        if (cis == 1) {
#pragma unroll
            for (int i = 0; i < R; i++)
                *reinterpret_cast<float4*>(&Ps[((rgR + i) * F_ + f) * 4]) = zh[i];
        }
        __syncthreads();
        if (cis == 0) {
#pragma unroll
            for (int i = 0; i < R; i++) {
                const float4 p = *reinterpret_cast<const float4*>(
                    &Ps[((rgR + i) * F_ + f) * 4]);
                zh[i].x += p.x; zh[i].y += p.y; zh[i].z += p.z; zh[i].w += p.w;
            }
        }
    }

    if (cis == 0) {
        const size_t btL = ((size_t)b * TT + t) * LL;
#pragma unroll
        for (int i = 0; i < R; i++) {
            const int l = l0 + rgR + i;
            const float4 z4 = *reinterpret_cast<const float4*>(
                &xz[(btL + l) * (size_t)(4 * F_) + f * 4]);
            float zi = z4.x + zh[i].x;
            float zf = z4.y + zh[i].y;
            float zg = z4.z + zh[i].z;
            float zo = z4.w + zh[i].w;
            float ig = hsig(zi), fg = hsig(zf);
            float gg = tanhf(zg), og = hsig(zo);
            size_t soff = ((size_t)b * LL + l) * F_ + f;
            float cp = (t > 0) ? cstate[soff] : 0.0f;
            float cn = fg * cp + ig * gg;
            float hn = og * tanhf(cn);
            cstate[soff] = cn;
            hnext[soff] = hn;
            if (OUTW) {
                // out[b][ue][spu][n*4+bit]; f = ue*8 + spu*4 + bit; n = t*L + l
                int ue = f >> 3, spu = (f >> 2) & 1, bit = f & 3;
                size_t n = (size_t)t * LL + l;
                dout[(((size_t)b * 4 + ue) * 2 + spu) * ((size_t)TT * LL * 4) + n * 4 + bit] = hn;
            } else {
                float v = hn;
                if (RESID) v += seq[(btL + l) * F_ + f];   // same idx, same thread
                seq[(btL + l) * F_ + f] = v;
            }
        }
    }
}

// ---------------------------------------------------------------------------
extern "C" void kernel_launch(void* const* d_in, const int* in_sizes, int n_in,
                              void* d_out, int out_size, void* d_ws, size_t ws_size,
                              hipStream_t stream)
{
    (void)in_sizes; (void)n_in; (void)out_size; (void)ws_size;
    const float* y_ri   = (const float*)d_in[0];
    const float* h_ri   = (const float*)d_in[1];
    const float* evar   = (const float*)d_in[2];
    const float* no     = (const float*)d_in[3];
    const float* wx_in  = (const float*)d_in[4];
    const float* wh_in  = (const float*)d_in[5];
    const float* b_in   = (const float*)d_in[6];
    const float* wx_r0  = (const float*)d_in[7];
    const float* wh_r0  = (const float*)d_in[8];
    const float* b_r0   = (const float*)d_in[9];
    const float* wx_r1  = (const float*)d_in[10];
    const float* wh_r1  = (const float*)d_in[11];
    const float* b_r1   = (const float*)d_in[12];
    const float* wx_out = (const float*)d_in[13];
    const float* wh_out = (const float*)d_in[14];
    const float* b_out  = (const float*)d_in[15];

    float* ws = (float*)d_ws;
    float* dout = (float*)d_out;

    {
        int blocks = (int)((PREP_TOTAL + 255) / 256);
        prep_weights_kernel<<<blocks, 256, 0, stream>>>(
            wx_in, wh_in, b_in, wx_r0, wh_r0, b_r0,
            wx_r1, wh_r1, b_r1, wx_out, wh_out, b_out, ws);
    }
    {
        long long total = (long long)BB * TT * LL * CINP;
        int blocks = (int)((total + 255) / 256);
        build_features_kernel<<<blocks, 256, 0, stream>>>(
            y_ri, h_ri, evar, no, ws + OFF_Z0);
    }

    float* hA = ws + OFF_HA;
    float* hB = ws + OFF_HB;
    float* cs = ws + OFF_CS;
    float* seq = ws + OFF_SEQ;
    const dim3 g256(12, BB * TT, 2);
    const dim3 g128(12, BB * TT, 1);
    const int stepGrid = BB * (LL / 8);          // 384 blocks

    // ---- layer in: Cin=297(p304) -> F=64
    xz_gemm_kernel<<<g256, 256, 0, stream>>>(
        ws + OFF_Z0, CINP, ws + OFF_WXIN, ws + OFF_BIN, ws + OFF_XZ, 256);
    for (int t = 0; t < TT; t++)
        lstm_step_kernel<64, false, false><<<stepGrid, 512, 0, stream>>>(
            ws + OFF_XZ, (const float4*)(ws + OFF_WHIN),
            (t & 1) ? hB : hA, (t & 1) ? hA : hB, cs, seq, nullptr, t);

    // ---- layer r0 (+residual, in-place on seq)
    xz_gemm_kernel<<<g256, 256, 0, stream>>>(
        seq, 64, ws + OFF_WXR0, ws + OFF_BR0, ws + OFF_XZ, 256);
    for (int t = 0; t < TT; t++)
        lstm_step_kernel<64, true, false><<<stepGrid, 512, 0, stream>>>(
            ws + OFF_XZ, (const float4*)(ws + OFF_WHR0),
            (t & 1) ? hB : hA, (t & 1) ? hA : hB, cs, seq, nullptr, t);

    // ---- layer r1 (+residual, in-place on seq)
    xz_gemm_kernel<<<g256, 256, 0, stream>>>(
        seq, 64, ws + OFF_WXR1, ws + OFF_BR1, ws + OFF_XZ, 256);
    for (int t = 0; t < TT; t++)
        lstm_step_kernel<64, true, false><<<stepGrid, 512, 0, stream>>>(
            ws + OFF_XZ, (const float4*)(ws + OFF_WHR1),
            (t & 1) ? hB : hA, (t & 1) ? hA : hB, cs, seq, nullptr, t);

    // ---- layer out: F=32, writes d_out (f32, transposed layout)
    xz_gemm_kernel<<<g128, 256, 0, stream>>>(
        seq, 64, ws + OFF_WXOUT, ws + OFF_BOUT, ws + OFF_XZ, 128);
    for (int t = 0; t < TT; t++)
        lstm_step_kernel<32, false, true><<<stepGrid, 256, 0, stream>>>(
            ws + OFF_XZ, (const float4*)(ws + OFF_WHOUT),
            (t & 1) ? hB : hA, (t & 1) ? hA : hB, cs, nullptr, dout, t);
}